// Round 6
// baseline (296.027 us; speedup 1.0000x reference)
//
#include <hip/hip_runtime.h>
#include <stdint.h>

typedef __attribute__((ext_vector_type(8))) short bf8_t;
typedef __attribute__((ext_vector_type(4))) float f4_t;

#define D_MODEL 1024
#define SEQ 2048
#define NB 4
#define NH 16
#define HD 64
#define MROWS (NB * SEQ)
// Q pre-scale folds 1/sqrt(64) and log2(e): scores land in exp2 domain
#define QSCALE 0.1803368801111204f

__device__ __forceinline__ uint16_t f2bf(float f) {
  uint32_t u = __builtin_bit_cast(uint32_t, f);
  u += 0x7FFFu + ((u >> 16) & 1u);
  return (uint16_t)(u >> 16);
}

__device__ __forceinline__ void gload16(const void* g, void* l) {
  __builtin_amdgcn_global_load_lds(
      (const __attribute__((address_space(1))) void*)g,
      (__attribute__((address_space(3))) void*)l, 16, 0, 0);
}

// ---- fp32 -> bf16 elementwise (vectorized) ----
__global__ void k_cvt(const float* __restrict__ in, uint16_t* __restrict__ out, int n4) {
  int i = blockIdx.x * blockDim.x + threadIdx.x;
  if (i >= n4) return;
  float4 v = ((const float4*)in)[i];
  ushort4 o;
  o.x = f2bf(v.x); o.y = f2bf(v.y); o.z = f2bf(v.z); o.w = f2bf(v.w);
  ((ushort4*)out)[i] = o;
}

// ---- transpose+convert: in [K][N] fp32 -> out [N][K] bf16 ----
__global__ void k_tcvt(const float* __restrict__ in, uint16_t* __restrict__ out, int K, int N) {
  __shared__ float tile[32][33];
  int nb = blockIdx.x * 32, kb = blockIdx.y * 32;
  int tx = threadIdx.x & 31, ty = threadIdx.x >> 5;
#pragma unroll
  for (int i = 0; i < 4; ++i)
    tile[ty + i * 8][tx] = in[(size_t)(kb + ty + i * 8) * N + nb + tx];
  __syncthreads();
#pragma unroll
  for (int i = 0; i < 4; ++i)
    out[(size_t)(nb + ty + i * 8) * K + kb + tx] = f2bf(tile[tx][ty + i * 8]);
}

// ---- 8-phase deep-pipelined GEMM mainloop (T2+T3+T4+T5, m201 template) ----
// BM=256, BK=64, 512 thr (8 waves = 2M x 4N), per-wave out 128 x (NREP*16).
// NO sched_barrier(0) in the phase body (m141: order-pinning halves perf);
// the asm waitcnts' "memory" clobbers are the only compiler fences, placed
// exactly at the hazard boundaries of the staging ledger.
template <int NREP>  // BN = NREP*64; B groups per K-tile = NREP
__device__ __forceinline__ void mainloop8p(const uint16_t* __restrict__ A,
                                           const uint16_t* __restrict__ Bt,
                                           int mBase, int nBase,
                                           uint16_t* __restrict__ AsB,
                                           uint16_t* __restrict__ BsB,
                                           f4_t (&acc)[8][NREP]) {
  constexpr int AELEM = 256 * 64;          // per-buffer A elements
  constexpr int BELEM = NREP * 64 * 64;    // per-buffer B elements
  const int t = threadIdx.x, lane = t & 63;
  const int g = lane >> 4, a = lane & 15;
  const int wave = t >> 6, wm = wave >> 2, wn = wave & 3;
  const int sr = t >> 3;                   // staging row in 64-row group
  const int sc = (t & 7) ^ (sr & 7);       // pre-swizzled source granule

  const uint16_t* Ag[4];
#pragma unroll
  for (int l = 0; l < 4; ++l)
    Ag[l] = A + (size_t)(mBase + l * 64 + sr) * D_MODEL + sc * 8;
  const uint16_t* Bg[NREP];
#pragma unroll
  for (int l = 0; l < NREP; ++l)
    Bg[l] = Bt + (size_t)(nBase + l * 64 + sr) * D_MODEL + sc * 8;

  auto stageA = [&](int kt, int h) {  // groups {h, h+2}
    int buf = kt & 1;
#pragma unroll
    for (int l = h; l < 4; l += 2)
      gload16(Ag[l] + kt * 64, AsB + buf * AELEM + (l * 512 + t) * 8);
  };
  auto stageB = [&](int kt, int h) {  // groups [h*NREP/2, (h+1)*NREP/2)
    int buf = kt & 1;
#pragma unroll
    for (int l = h * (NREP / 2); l < (h + 1) * (NREP / 2); ++l)
      gload16(Bg[l] + kt * 64, BsB + buf * BELEM + (l * 512 + t) * 8);
  };

  // prologue: kt0 fully + kt1 {B0, Ah0, B1}; vmcnt leaves kt1's 3 halves live
  stageA(0, 0); stageA(0, 1); stageB(0, 0); stageB(0, 1);
  stageB(1, 0); stageA(1, 0); stageB(1, 1);
  if constexpr (NREP == 4) asm volatile("s_waitcnt vmcnt(6)" ::: "memory");
  else                     asm volatile("s_waitcnt vmcnt(4)" ::: "memory");
  __builtin_amdgcn_s_barrier();

  bf8_t bfr[NREP][2];
  // stage pattern per phase (rel. to ka): A/B, kt offset, half
  constexpr int stA[8] = {1, 0, 1, 0, 1, 0, 1, 0};
  constexpr int stK[8] = {1, 2, 2, 2, 2, 3, 3, 3};
  constexpr int stH[8] = {1, 0, 0, 1, 1, 0, 0, 1};

#pragma unroll 1
  for (int it = 0; it < 8; ++it) {
    const int ka = 2 * it;
#pragma unroll
    for (int p = 0; p < 8; ++p) {
      const int s = p & 3;
      const int buf = p >> 2;            // ka even -> buf0 phases 0-3, buf1 4-7
      const char* Ab = (const char*)(AsB + buf * AELEM);
      const char* Bb = (const char*)(BsB + buf * BELEM);
      // --- ds-reads for this phase ---
      if (s == 0) {
#pragma unroll
        for (int ni = 0; ni < NREP; ++ni) {
          int row = wn * (NREP * 16) + ni * 16 + a;
#pragma unroll
          for (int kk = 0; kk < 2; ++kk)
            bfr[ni][kk] = *(const bf8_t*)(Bb + row * 128 + (((4 * kk + g) ^ (row & 7)) * 16));
        }
      }
      bf8_t af[2][2];
#pragma unroll
      for (int mm = 0; mm < 2; ++mm) {
        int row = wm * 128 + (2 * s + mm) * 16 + a;
#pragma unroll
        for (int kk = 0; kk < 2; ++kk)
          af[mm][kk] = *(const bf8_t*)(Ab + row * 128 + (((4 * kk + g) ^ (row & 7)) * 16));
      }
      // --- stage one half-tile (ledger-verified region freedom) ---
      {
        int tkt = ka + stK[p];
        if (tkt < D_MODEL / 64) {
          if (stA[p]) stageA(tkt, stH[p]);
          else        stageB(tkt, stH[p]);
        }
      }
      // --- barrier 1: all waves issued reads+stage ---
      __builtin_amdgcn_s_barrier();
      asm volatile("s_waitcnt lgkmcnt(0)" ::: "memory");
      // --- MFMA cluster ---
      __builtin_amdgcn_s_setprio(1);
#pragma unroll
      for (int mm = 0; mm < 2; ++mm)
#pragma unroll
        for (int ni = 0; ni < NREP; ++ni) {
          acc[2 * s + mm][ni] = __builtin_amdgcn_mfma_f32_16x16x32_bf16(af[mm][0], bfr[ni][0], acc[2 * s + mm][ni], 0, 0, 0);
          acc[2 * s + mm][ni] = __builtin_amdgcn_mfma_f32_16x16x32_bf16(af[mm][1], bfr[ni][1], acc[2 * s + mm][ni], 0, 0, 0);
        }
      __builtin_amdgcn_s_setprio(0);
      // --- counted vmcnt only at phases 4 and 8 ---
      if (p == 3 || p == 7) {
        if (it == 7)             asm volatile("s_waitcnt vmcnt(0)" ::: "memory");
        else if constexpr (NREP == 4) asm volatile("s_waitcnt vmcnt(6)" ::: "memory");
        else                     asm volatile("s_waitcnt vmcnt(4)" ::: "memory");
      }
      // --- barrier 2: phase boundary ---
      __builtin_amdgcn_s_barrier();
    }
  }
}

// ---- QKV GEMM: 256x256 8-phase; epilogue -> Q (scaled), K, V^T (s-permuted) ----
__global__ __launch_bounds__(512, 2) void k_gemm_qkv(
    const uint16_t* __restrict__ A, const uint16_t* __restrict__ Bt,
    const float* __restrict__ bias,
    uint16_t* __restrict__ Qb, uint16_t* __restrict__ Kb, uint16_t* __restrict__ VTb) {
  __shared__ uint16_t As[2][256 * 64];
  __shared__ uint16_t Bs[2][256 * 64];
  int flat = blockIdx.x;
  int swz = (flat & 7) * 48 + (flat >> 3);   // 384 blocks, XCD-chunked, bijective
  int bx = swz % 12, by = swz / 12;
  int mBase = by * 256, nBase = bx * 256;
  f4_t acc[8][4] = {};
  mainloop8p<4>(A, Bt, mBase, nBase, &As[0][0], &Bs[0][0], acc);
  const int lane = threadIdx.x & 63, g = lane >> 4, a = lane & 15;
  const int wave = threadIdx.x >> 6, wm = wave >> 2, wn = wave & 3;
  float bi[4];
#pragma unroll
  for (int ni = 0; ni < 4; ++ni) bi[ni] = bias[nBase + wn * 64 + ni * 16 + a];
#pragma unroll
  for (int mi = 0; mi < 8; ++mi)
#pragma unroll
    for (int ni = 0; ni < 4; ++ni)
#pragma unroll
      for (int i = 0; i < 4; ++i) {
        int m = mBase + wm * 128 + mi * 16 + 4 * g + i;
        int n = nBase + wn * 64 + ni * 16 + a;
        float v = acc[mi][ni][i] + bi[ni];
        int b = m >> 11, s = m & 2047;
        int which = n >> 10, hn = n & 1023;
        int h = hn >> 6, d = hn & 63;
        size_t bh = (size_t)(b * NH + h);
        if (which == 0)      Qb[(bh * SEQ + s) * HD + d] = f2bf(v * QSCALE);
        else if (which == 1) Kb[(bh * SEQ + s) * HD + d] = f2bf(v);
        else {
          // store V^T with s-cols bit-permuted within each 64-chunk:
          // sigma: b5,b4,b3:2,b1:0 = kx,n,g,m -> kx,g,n,m  (so PV B-frag = b128)
          int x = s & 63;
          int sp = (s & ~63) | (x & 0x23) | ((x & 0x0C) << 1) | ((x & 0x10) >> 2);
          VTb[(bh * HD + d) * SEQ + sp] = f2bf(v);
        }
      }
}

// ---- proj GEMM: 256x128 8-phase (grid 256 = 1 block/CU, no tail), fp32 out ----
__global__ __launch_bounds__(512, 2) void k_gemm_proj(
    const uint16_t* __restrict__ A, const uint16_t* __restrict__ Bt,
    const float* __restrict__ bias, float* __restrict__ out) {
  __shared__ uint16_t As[2][256 * 64];
  __shared__ uint16_t Bs[2][128 * 64];
  int flat = blockIdx.x;
  int swz = (flat & 7) * 32 + (flat >> 3);
  int bx = swz % 8, by = swz / 8;
  int mBase = by * 256, nBase = bx * 128;
  f4_t acc[8][2] = {};
  mainloop8p<2>(A, Bt, mBase, nBase, &As[0][0], &Bs[0][0], acc);
  const int lane = threadIdx.x & 63, g = lane >> 4, a = lane & 15;
  const int wave = threadIdx.x >> 6, wm = wave >> 2, wn = wave & 3;
  float bi[2];
#pragma unroll
  for (int ni = 0; ni < 2; ++ni) bi[ni] = bias[nBase + wn * 32 + ni * 16 + a];
#pragma unroll
  for (int mi = 0; mi < 8; ++mi)
#pragma unroll
    for (int ni = 0; ni < 2; ++ni)
#pragma unroll
      for (int i = 0; i < 4; ++i) {
        int m = mBase + wm * 128 + mi * 16 + 4 * g + i;
        int n = nBase + wn * 32 + ni * 16 + a;
        out[(size_t)m * D_MODEL + n] = acc[mi][ni][i] + bi[ni];
      }
}

// ---- flash attention, causal (unchanged; V s-permuted -> b128 PV reads) ----
__global__ __launch_bounds__(512, 4) void k_attn(
    const uint16_t* __restrict__ Qb, const uint16_t* __restrict__ Kb,
    const uint16_t* __restrict__ VTb, uint16_t* __restrict__ Yb) {
  __shared__ uint16_t Ks[2][64 * 64];
  __shared__ uint16_t Vs[2][64 * 64];
  const int t = threadIdx.x, lane = t & 63, wave = t >> 6;
  const int g = lane >> 4, a = lane & 15;
  const int bh = blockIdx.x, pr = blockIdx.y;
  const int b = bh >> 4, h = bh & 15;

  const int sr = t >> 3;
  const int scol = (t & 7) ^ (sr & 7);
  const uint16_t* Kg = Kb + ((size_t)bh * SEQ + sr) * HD + scol * 8;
  const uint16_t* Vg = VTb + ((size_t)bh * HD + sr) * SEQ + scol * 8;

#pragma unroll 1
  for (int seg = 0; seg < 2; ++seg) {
    const int qt = seg ? (15 - pr) : pr;
    const int qrow0 = qt * 128 + wave * 16;
    const uint16_t* Qrow = Qb + ((size_t)bh * SEQ + qrow0 + a) * HD;
    bf8_t aq[2];
    aq[0] = *(const bf8_t*)(Qrow + g * 8);
    aq[1] = *(const bf8_t*)(Qrow + g * 8 + 32);
    float m_i = -__builtin_inff(), l_i = 0.f;
    f4_t O[4] = {};

    const int nt = 2 * qt + 2;
    gload16(Kg, Ks[0] + t * 8);
    gload16(Vg, Vs[0] + t * 8);

    for (int kt = 0; kt < nt; ++kt) {
      const int cur = kt & 1;
      if (kt + 1 < nt) {
        gload16(Kg + (size_t)(kt + 1) * 64 * HD, Ks[cur ^ 1] + t * 8);
        gload16(Vg + (kt + 1) * 64, Vs[cur ^ 1] + t * 8);
        asm volatile("s_waitcnt vmcnt(2)" ::: "memory");
      } else {
        asm volatile("s_waitcnt vmcnt(0)" ::: "memory");
      }
      __builtin_amdgcn_s_barrier();

      const uint16_t* Kt = Ks[cur];
      const uint16_t* Vt = Vs[cur];
      if (kt * 64 <= qrow0 + 15) {
        f4_t sacc[4] = {};
#pragma unroll
        for (int f = 0; f < 4; ++f) {
          int kr = f * 16 + a;
#pragma unroll
          for (int kx = 0; kx < 2; ++kx) {
            int gl = g + kx * 4;
            bf8_t bk = *(const bf8_t*)((const char*)Kt + kr * 128 + ((gl ^ (kr & 7)) * 16));
            sacc[f] = __builtin_amdgcn_mfma_f32_16x16x32_bf16(bk, aq[kx], sacc[f], 0, 0, 0);
          }
        }
        if (kt >= 2 * qt) {
          int q = qrow0 + a;
#pragma unroll
          for (int f = 0; f < 4; ++f)
#pragma unroll
            for (int i = 0; i < 4; ++i) {
              int key = kt * 64 + f * 16 + g * 4 + i;
              if (key > q) sacc[f][i] = -__builtin_inff();
            }
        }
        float mx = sacc[0][0];
#pragma unroll
        for (int f = 0; f < 4; ++f)
#pragma unroll
          for (int i = 0; i < 4; ++i) mx = fmaxf(mx, sacc[f][i]);
        mx = fmaxf(mx, __shfl_xor(mx, 16));
        mx = fmaxf(mx, __shfl_xor(mx, 32));
        if (__any(mx > m_i + 8.0f)) {
          float mN = fmaxf(m_i, mx);
          float sc2 = exp2f(m_i - mN);
          m_i = mN;
          l_i *= sc2;
#pragma unroll
          for (int i = 0; i < 4; ++i) {
            float s4 = __shfl(sc2, (lane & 48) | (g * 4 + i));
#pragma unroll
            for (int f2 = 0; f2 < 4; ++f2) O[f2][i] *= s4;
          }
        }
        float pvv[4][4];
        float sm = 0.f;
#pragma unroll
        for (int f = 0; f < 4; ++f)
#pragma unroll
          for (int i = 0; i < 4; ++i) {
            pvv[f][i] = exp2f(sacc[f][i] - m_i);
            sm += pvv[f][i];
          }
        sm += __shfl_xor(sm, 16);
        sm += __shfl_xor(sm, 32);
        l_i += sm;
        bf8_t pa[2];
#pragma unroll
        for (int kx = 0; kx < 2; ++kx)
#pragma unroll
          for (int j = 0; j < 8; ++j)
            pa[kx][j] = (short)f2bf(pvv[2 * kx + (j >> 2)][j & 3]);
        // V^T stored s-permuted: B-frag is one swizzled b128 (conflict-free)
#pragma unroll
        for (int kx = 0; kx < 2; ++kx)
#pragma unroll
          for (int f2 = 0; f2 < 4; ++f2) {
            int rv = f2 * 16 + a;
            bf8_t bv = *(const bf8_t*)((const char*)Vt + rv * 128 + (((4 * kx + g) ^ (rv & 7)) * 16));
            O[f2] = __builtin_amdgcn_mfma_f32_16x16x32_bf16(pa[kx], bv, O[f2], 0, 0, 0);
          }
      }
      asm volatile("s_waitcnt lgkmcnt(0)" ::: "memory");
      __builtin_amdgcn_s_barrier();
    }
    float rinv[4];
#pragma unroll
    for (int i = 0; i < 4; ++i)
      rinv[i] = 1.0f / __shfl(l_i, (lane & 48) | (g * 4 + i));
#pragma unroll
    for (int f2 = 0; f2 < 4; ++f2)
#pragma unroll
      for (int i = 0; i < 4; ++i) {
        int q = qrow0 + g * 4 + i;
        int d = f2 * 16 + a;
        Yb[((size_t)b * SEQ + q) * D_MODEL + h * HD + d] = f2bf(O[f2][i] * rinv[i]);
      }
  }
}

extern "C" void kernel_launch(void* const* d_in, const int* in_sizes, int n_in,
                              void* d_out, int out_size, void* d_ws, size_t ws_size,
                              hipStream_t stream) {
  const float* x     = (const float*)d_in[0];
  const float* wqkv  = (const float*)d_in[1];
  const float* bqkv  = (const float*)d_in[2];
  const float* wproj = (const float*)d_in[3];
  const float* bproj = (const float*)d_in[4];
  float* out = (float*)d_out;
  char* ws = (char*)d_ws;
  uint16_t* xb     = (uint16_t*)(ws);                          // 16 MiB
  uint16_t* wqkvT  = (uint16_t*)(ws + 16777216);               // 6 MiB
  uint16_t* wprojT = (uint16_t*)(ws + 16777216 + 6291456);     // 2 MiB
  uint16_t* Qb     = (uint16_t*)(ws + 25165824);               // 16 MiB [B,H,S,64]
  uint16_t* Kb     = (uint16_t*)(ws + 25165824 + 16777216);    // 16 MiB [B,H,S,64]
  uint16_t* VTb    = (uint16_t*)(ws + 25165824 + 2 * 16777216);// 16 MiB [B,H,64,S] (s-permuted)
  uint16_t* Yb     = (uint16_t*)(ws + 25165824 + 3 * 16777216);// 16 MiB [B,S,H*64]

  k_cvt<<<dim3(MROWS * D_MODEL / 4 / 256), dim3(256), 0, stream>>>(x, xb, MROWS * D_MODEL / 4);
  k_tcvt<<<dim3(3 * D_MODEL / 32, D_MODEL / 32), dim3(256), 0, stream>>>(wqkv, wqkvT, D_MODEL, 3 * D_MODEL);
  k_tcvt<<<dim3(D_MODEL / 32, D_MODEL / 32), dim3(256), 0, stream>>>(wproj, wprojT, D_MODEL, D_MODEL);
  k_gemm_qkv<<<dim3(384), dim3(512), 0, stream>>>(xb, wqkvT, bqkv, Qb, Kb, VTb);
  k_attn<<<dim3(NB * NH, 8), dim3(512), 0, stream>>>(Qb, Kb, VTb, Yb);
  k_gemm_proj<<<dim3(256), dim3(512), 0, stream>>>(Yb, wprojT, bproj, out);
}

// Round 7
// 260.955 us; speedup vs baseline: 1.1344x; 1.1344x over previous
//
#include <hip/hip_runtime.h>
#include <stdint.h>

typedef __attribute__((ext_vector_type(8))) short bf8_t;
typedef __attribute__((ext_vector_type(4))) float f4_t;

#define D_MODEL 1024
#define SEQ 2048
#define NB 4
#define NH 16
#define HD 64
#define MROWS (NB * SEQ)
// Q pre-scale folds 1/sqrt(64) and log2(e): scores land in exp2 domain
#define QSCALE 0.1803368801111204f

__device__ __forceinline__ uint16_t f2bf(float f) {
  uint32_t u = __builtin_bit_cast(uint32_t, f);
  u += 0x7FFFu + ((u >> 16) & 1u);
  return (uint16_t)(u >> 16);
}

__device__ __forceinline__ void gload16(const void* g, void* l) {
  __builtin_amdgcn_global_load_lds(
      (const __attribute__((address_space(1))) void*)g,
      (__attribute__((address_space(3))) void*)l, 16, 0, 0);
}

// ---- fp32 -> bf16 elementwise (vectorized) ----
__global__ void k_cvt(const float* __restrict__ in, uint16_t* __restrict__ out, int n4) {
  int i = blockIdx.x * blockDim.x + threadIdx.x;
  if (i >= n4) return;
  float4 v = ((const float4*)in)[i];
  ushort4 o;
  o.x = f2bf(v.x); o.y = f2bf(v.y); o.z = f2bf(v.z); o.w = f2bf(v.w);
  ((ushort4*)out)[i] = o;
}

// ---- transpose+convert: in [K][N] fp32 -> out [N][K] bf16 ----
__global__ void k_tcvt(const float* __restrict__ in, uint16_t* __restrict__ out, int K, int N) {
  __shared__ float tile[32][33];
  int nb = blockIdx.x * 32, kb = blockIdx.y * 32;
  int tx = threadIdx.x & 31, ty = threadIdx.x >> 5;
#pragma unroll
  for (int i = 0; i < 4; ++i)
    tile[ty + i * 8][tx] = in[(size_t)(kb + ty + i * 8) * N + nb + tx];
  __syncthreads();
#pragma unroll
  for (int i = 0; i < 4; ++i)
    out[(size_t)(nb + ty + i * 8) * K + kb + tx] = f2bf(tile[tx][ty + i * 8]);
}

// ---- 8-phase deep-pipelined GEMM mainloop (unchanged from r6) ----
template <int NREP>  // BN = NREP*64; B groups per K-tile = NREP
__device__ __forceinline__ void mainloop8p(const uint16_t* __restrict__ A,
                                           const uint16_t* __restrict__ Bt,
                                           int mBase, int nBase,
                                           uint16_t* __restrict__ AsB,
                                           uint16_t* __restrict__ BsB,
                                           f4_t (&acc)[8][NREP]) {
  constexpr int AELEM = 256 * 64;          // per-buffer A elements
  constexpr int BELEM = NREP * 64 * 64;    // per-buffer B elements
  const int t = threadIdx.x, lane = t & 63;
  const int g = lane >> 4, a = lane & 15;
  const int wave = t >> 6, wm = wave >> 2, wn = wave & 3;
  const int sr = t >> 3;                   // staging row in 64-row group
  const int sc = (t & 7) ^ (sr & 7);       // pre-swizzled source granule

  const uint16_t* Ag[4];
#pragma unroll
  for (int l = 0; l < 4; ++l)
    Ag[l] = A + (size_t)(mBase + l * 64 + sr) * D_MODEL + sc * 8;
  const uint16_t* Bg[NREP];
#pragma unroll
  for (int l = 0; l < NREP; ++l)
    Bg[l] = Bt + (size_t)(nBase + l * 64 + sr) * D_MODEL + sc * 8;

  auto stageA = [&](int kt, int h) {  // groups {h, h+2}
    int buf = kt & 1;
#pragma unroll
    for (int l = h; l < 4; l += 2)
      gload16(Ag[l] + kt * 64, AsB + buf * AELEM + (l * 512 + t) * 8);
  };
  auto stageB = [&](int kt, int h) {  // groups [h*NREP/2, (h+1)*NREP/2)
    int buf = kt & 1;
#pragma unroll
    for (int l = h * (NREP / 2); l < (h + 1) * (NREP / 2); ++l)
      gload16(Bg[l] + kt * 64, BsB + buf * BELEM + (l * 512 + t) * 8);
  };

  // prologue: kt0 fully + kt1 {B0, Ah0, B1}; vmcnt leaves kt1's 3 halves live
  stageA(0, 0); stageA(0, 1); stageB(0, 0); stageB(0, 1);
  stageB(1, 0); stageA(1, 0); stageB(1, 1);
  if constexpr (NREP == 4) asm volatile("s_waitcnt vmcnt(6)" ::: "memory");
  else                     asm volatile("s_waitcnt vmcnt(4)" ::: "memory");
  __builtin_amdgcn_s_barrier();

  bf8_t bfr[NREP][2];
  // stage pattern per phase (rel. to ka): A/B, kt offset, half
  constexpr int stA[8] = {1, 0, 1, 0, 1, 0, 1, 0};
  constexpr int stK[8] = {1, 2, 2, 2, 2, 3, 3, 3};
  constexpr int stH[8] = {1, 0, 0, 1, 1, 0, 0, 1};

#pragma unroll 1
  for (int it = 0; it < 8; ++it) {
    const int ka = 2 * it;
#pragma unroll
    for (int p = 0; p < 8; ++p) {
      const int s = p & 3;
      const int buf = p >> 2;            // ka even -> buf0 phases 0-3, buf1 4-7
      const char* Ab = (const char*)(AsB + buf * AELEM);
      const char* Bb = (const char*)(BsB + buf * BELEM);
      // --- ds-reads for this phase ---
      if (s == 0) {
#pragma unroll
        for (int ni = 0; ni < NREP; ++ni) {
          int row = wn * (NREP * 16) + ni * 16 + a;
#pragma unroll
          for (int kk = 0; kk < 2; ++kk)
            bfr[ni][kk] = *(const bf8_t*)(Bb + row * 128 + (((4 * kk + g) ^ (row & 7)) * 16));
        }
      }
      bf8_t af[2][2];
#pragma unroll
      for (int mm = 0; mm < 2; ++mm) {
        int row = wm * 128 + (2 * s + mm) * 16 + a;
#pragma unroll
        for (int kk = 0; kk < 2; ++kk)
          af[mm][kk] = *(const bf8_t*)(Ab + row * 128 + (((4 * kk + g) ^ (row & 7)) * 16));
      }
      // --- stage one half-tile ---
      {
        int tkt = ka + stK[p];
        if (tkt < D_MODEL / 64) {
          if (stA[p]) stageA(tkt, stH[p]);
          else        stageB(tkt, stH[p]);
        }
      }
      // --- barrier 1: all waves issued reads+stage ---
      __builtin_amdgcn_s_barrier();
      asm volatile("s_waitcnt lgkmcnt(0)" ::: "memory");
      // --- MFMA cluster ---
      __builtin_amdgcn_s_setprio(1);
#pragma unroll
      for (int mm = 0; mm < 2; ++mm)
#pragma unroll
        for (int ni = 0; ni < NREP; ++ni) {
          acc[2 * s + mm][ni] = __builtin_amdgcn_mfma_f32_16x16x32_bf16(af[mm][0], bfr[ni][0], acc[2 * s + mm][ni], 0, 0, 0);
          acc[2 * s + mm][ni] = __builtin_amdgcn_mfma_f32_16x16x32_bf16(af[mm][1], bfr[ni][1], acc[2 * s + mm][ni], 0, 0, 0);
        }
      __builtin_amdgcn_s_setprio(0);
      // --- counted vmcnt only at phases 4 and 8 ---
      if (p == 3 || p == 7) {
        if (it == 7)             asm volatile("s_waitcnt vmcnt(0)" ::: "memory");
        else if constexpr (NREP == 4) asm volatile("s_waitcnt vmcnt(6)" ::: "memory");
        else                     asm volatile("s_waitcnt vmcnt(4)" ::: "memory");
      }
      // --- barrier 2: phase boundary ---
      __builtin_amdgcn_s_barrier();
    }
  }
}

// ---- QKV GEMM: 256x256 8-phase. Each block is purely Q, K, or V (1024%256==0).
// V-blocks: LDS-bounce transpose -> coalesced V^T stores (kills the 4KB-stride
// 2-byte scatter that was ~half the kernel time). Q/K: direct 32B-segment
// stores (benign). ----
__global__ __launch_bounds__(512, 2) void k_gemm_qkv(
    const uint16_t* __restrict__ A, const uint16_t* __restrict__ Bt,
    const float* __restrict__ bias,
    uint16_t* __restrict__ Qb, uint16_t* __restrict__ Kb, uint16_t* __restrict__ VTb) {
  __shared__ uint16_t SM[65536];   // 128 KB: [0,32768) = A dbuf, [32768,65536) = B dbuf
  uint16_t* As = SM;
  uint16_t* Bs = SM + 32768;
  int flat = blockIdx.x;
  int swz = (flat & 7) * 48 + (flat >> 3);   // 384 blocks, XCD-chunked, bijective
  int bx = swz % 12, by = swz / 12;
  int mBase = by * 256, nBase = bx * 256;
  f4_t acc[8][4] = {};
  mainloop8p<4>(A, Bt, mBase, nBase, As, Bs, acc);
  const int t = threadIdx.x;
  const int lane = t & 63, g = lane >> 4, a = lane & 15;
  const int wave = t >> 6, wm = wave >> 2, wn = wave & 3;
  float bi[4];
#pragma unroll
  for (int ni = 0; ni < 4; ++ni) bi[ni] = bias[nBase + wn * 64 + ni * 16 + a];

  if (nBase >= 2048) {
    // ---- V-block: acc -> LDS [n][m] (transposed, XOR-swizzled) ----
    char* VL = (char*)SM;  // 128 KB = 256 n x 256 m bf16 (staging LDS is free now)
#pragma unroll
    for (int mi = 0; mi < 8; ++mi)
#pragma unroll
      for (int ni = 0; ni < 4; ++ni) {
        int n_l = wn * 64 + ni * 16 + a;
        int m2 = (wm * 128 + mi * 16 + 4 * g) * 2;   // byte offset of 4-elem run
        ushort4 pk;
#pragma unroll
        for (int i = 0; i < 4; ++i)
          ((uint16_t*)&pk)[i] = f2bf(acc[mi][ni][i] + bi[ni]);
        *(ushort4*)(VL + n_l * 512 + (m2 ^ ((n_l & 7) << 4))) = pk;
      }
    asm volatile("s_waitcnt lgkmcnt(0)" ::: "memory");
    __builtin_amdgcn_s_barrier();
    // ---- coalesced V^T store: b128 along m, two 8B runs per 16B ----
    const int bb = mBase >> 11, s0 = mBase & 2047;
    const int nb2 = nBase - 2048;
#pragma unroll 1
    for (int it2 = 0; it2 < 16; ++it2) {
      int L = it2 * 512 + t;          // 8192 units: 256 n x 32 m-granules
      int mg = L & 31, n = L >> 5;
      bf8_t v = *(const bf8_t*)(VL + n * 512 + ((mg * 16) ^ ((n & 7) << 4)));
      int hn = nb2 + n, h = hn >> 6, d = hn & 63;
      int s = s0 + mg * 8;
      int x = s & 63;                 // bits 3..5 only (mg*8)
      int base = (x & 0x20) | ((x & 8) << 1) | ((x & 0x10) >> 2);  // sigma run base
      uint16_t* dst = VTb + ((size_t)(bb * NH + h) * HD + d) * SEQ + (s & ~63) + base;
      ushort4 lo, hi;
#pragma unroll
      for (int j = 0; j < 4; ++j) {
        ((uint16_t*)&lo)[j] = (uint16_t)((short)v[j]);
        ((uint16_t*)&hi)[j] = (uint16_t)((short)v[4 + j]);
      }
      *(ushort4*)dst = lo;            // sigma(x+j) = base + j  (j=0..3)
      *(ushort4*)(dst + 8) = hi;      // sigma(x+4+j) = base + 8 + j
    }
  } else {
    // ---- Q/K block: direct stores (32B segments) ----
    const bool isQ = nBase < 1024;
#pragma unroll
    for (int mi = 0; mi < 8; ++mi)
#pragma unroll
      for (int ni = 0; ni < 4; ++ni)
#pragma unroll
        for (int i = 0; i < 4; ++i) {
          int m = mBase + wm * 128 + mi * 16 + 4 * g + i;
          int n = nBase + wn * 64 + ni * 16 + a;
          float v = acc[mi][ni][i] + bi[ni];
          int b = m >> 11, s = m & 2047;
          int hn = n & 1023;
          int h = hn >> 6, d = hn & 63;
          size_t bh = (size_t)(b * NH + h);
          if (isQ) Qb[(bh * SEQ + s) * HD + d] = f2bf(v * QSCALE);
          else     Kb[(bh * SEQ + s) * HD + d] = f2bf(v);
        }
  }
}

// ---- proj GEMM: 256x128 8-phase (grid 256 = 1 block/CU), fp32 out (unchanged) ----
__global__ __launch_bounds__(512, 2) void k_gemm_proj(
    const uint16_t* __restrict__ A, const uint16_t* __restrict__ Bt,
    const float* __restrict__ bias, float* __restrict__ out) {
  __shared__ uint16_t SM[49152];   // 96 KB: A dbuf 64 KB + B dbuf 32 KB
  uint16_t* As = SM;
  uint16_t* Bs = SM + 32768;
  int flat = blockIdx.x;
  int swz = (flat & 7) * 32 + (flat >> 3);
  int bx = swz % 8, by = swz / 8;
  int mBase = by * 256, nBase = bx * 128;
  f4_t acc[8][2] = {};
  mainloop8p<2>(A, Bt, mBase, nBase, As, Bs, acc);
  const int lane = threadIdx.x & 63, g = lane >> 4, a = lane & 15;
  const int wave = threadIdx.x >> 6, wm = wave >> 2, wn = wave & 3;
  float bi[2];
#pragma unroll
  for (int ni = 0; ni < 2; ++ni) bi[ni] = bias[nBase + wn * 32 + ni * 16 + a];
#pragma unroll
  for (int mi = 0; mi < 8; ++mi)
#pragma unroll
    for (int ni = 0; ni < 2; ++ni)
#pragma unroll
      for (int i = 0; i < 4; ++i) {
        int m = mBase + wm * 128 + mi * 16 + 4 * g + i;
        int n = nBase + wn * 32 + ni * 16 + a;
        out[(size_t)m * D_MODEL + n] = acc[mi][ni][i] + bi[ni];
      }
}

// ---- flash attention, causal (unchanged; V s-permuted -> b128 PV reads) ----
__global__ __launch_bounds__(512, 4) void k_attn(
    const uint16_t* __restrict__ Qb, const uint16_t* __restrict__ Kb,
    const uint16_t* __restrict__ VTb, uint16_t* __restrict__ Yb) {
  __shared__ uint16_t Ks[2][64 * 64];
  __shared__ uint16_t Vs[2][64 * 64];
  const int t = threadIdx.x, lane = t & 63, wave = t >> 6;
  const int g = lane >> 4, a = lane & 15;
  const int bh = blockIdx.x, pr = blockIdx.y;
  const int b = bh >> 4, h = bh & 15;

  const int sr = t >> 3;
  const int scol = (t & 7) ^ (sr & 7);
  const uint16_t* Kg = Kb + ((size_t)bh * SEQ + sr) * HD + scol * 8;
  const uint16_t* Vg = VTb + ((size_t)bh * HD + sr) * SEQ + scol * 8;

#pragma unroll 1
  for (int seg = 0; seg < 2; ++seg) {
    const int qt = seg ? (15 - pr) : pr;
    const int qrow0 = qt * 128 + wave * 16;
    const uint16_t* Qrow = Qb + ((size_t)bh * SEQ + qrow0 + a) * HD;
    bf8_t aq[2];
    aq[0] = *(const bf8_t*)(Qrow + g * 8);
    aq[1] = *(const bf8_t*)(Qrow + g * 8 + 32);
    float m_i = -__builtin_inff(), l_i = 0.f;
    f4_t O[4] = {};

    const int nt = 2 * qt + 2;
    gload16(Kg, Ks[0] + t * 8);
    gload16(Vg, Vs[0] + t * 8);

    for (int kt = 0; kt < nt; ++kt) {
      const int cur = kt & 1;
      if (kt + 1 < nt) {
        gload16(Kg + (size_t)(kt + 1) * 64 * HD, Ks[cur ^ 1] + t * 8);
        gload16(Vg + (kt + 1) * 64, Vs[cur ^ 1] + t * 8);
        asm volatile("s_waitcnt vmcnt(2)" ::: "memory");
      } else {
        asm volatile("s_waitcnt vmcnt(0)" ::: "memory");
      }
      __builtin_amdgcn_s_barrier();

      const uint16_t* Kt = Ks[cur];
      const uint16_t* Vt = Vs[cur];
      if (kt * 64 <= qrow0 + 15) {
        f4_t sacc[4] = {};
#pragma unroll
        for (int f = 0; f < 4; ++f) {
          int kr = f * 16 + a;
#pragma unroll
          for (int kx = 0; kx < 2; ++kx) {
            int gl = g + kx * 4;
            bf8_t bk = *(const bf8_t*)((const char*)Kt + kr * 128 + ((gl ^ (kr & 7)) * 16));
            sacc[f] = __builtin_amdgcn_mfma_f32_16x16x32_bf16(bk, aq[kx], sacc[f], 0, 0, 0);
          }
        }
        if (kt >= 2 * qt) {
          int q = qrow0 + a;
#pragma unroll
          for (int f = 0; f < 4; ++f)
#pragma unroll
            for (int i = 0; i < 4; ++i) {
              int key = kt * 64 + f * 16 + g * 4 + i;
              if (key > q) sacc[f][i] = -__builtin_inff();
            }
        }
        float mx = sacc[0][0];
#pragma unroll
        for (int f = 0; f < 4; ++f)
#pragma unroll
          for (int i = 0; i < 4; ++i) mx = fmaxf(mx, sacc[f][i]);
        mx = fmaxf(mx, __shfl_xor(mx, 16));
        mx = fmaxf(mx, __shfl_xor(mx, 32));
        if (__any(mx > m_i + 8.0f)) {
          float mN = fmaxf(m_i, mx);
          float sc2 = exp2f(m_i - mN);
          m_i = mN;
          l_i *= sc2;
#pragma unroll
          for (int i = 0; i < 4; ++i) {
            float s4 = __shfl(sc2, (lane & 48) | (g * 4 + i));
#pragma unroll
            for (int f2 = 0; f2 < 4; ++f2) O[f2][i] *= s4;
          }
        }
        float pvv[4][4];
        float sm = 0.f;
#pragma unroll
        for (int f = 0; f < 4; ++f)
#pragma unroll
          for (int i = 0; i < 4; ++i) {
            pvv[f][i] = exp2f(sacc[f][i] - m_i);
            sm += pvv[f][i];
          }
        sm += __shfl_xor(sm, 16);
        sm += __shfl_xor(sm, 32);
        l_i += sm;
        bf8_t pa[2];
#pragma unroll
        for (int kx = 0; kx < 2; ++kx)
#pragma unroll
          for (int j = 0; j < 8; ++j)
            pa[kx][j] = (short)f2bf(pvv[2 * kx + (j >> 2)][j & 3]);
        // V^T stored s-permuted: B-frag is one swizzled b128 (conflict-free)
#pragma unroll
        for (int kx = 0; kx < 2; ++kx)
#pragma unroll
          for (int f2 = 0; f2 < 4; ++f2) {
            int rv = f2 * 16 + a;
            bf8_t bv = *(const bf8_t*)((const char*)Vt + rv * 128 + (((4 * kx + g) ^ (rv & 7)) * 16));
            O[f2] = __builtin_amdgcn_mfma_f32_16x16x32_bf16(pa[kx], bv, O[f2], 0, 0, 0);
          }
      }
      asm volatile("s_waitcnt lgkmcnt(0)" ::: "memory");
      __builtin_amdgcn_s_barrier();
    }
    float rinv[4];
#pragma unroll
    for (int i = 0; i < 4; ++i)
      rinv[i] = 1.0f / __shfl(l_i, (lane & 48) | (g * 4 + i));
#pragma unroll
    for (int f2 = 0; f2 < 4; ++f2)
#pragma unroll
      for (int i = 0; i < 4; ++i) {
        int q = qrow0 + g * 4 + i;
        int d = f2 * 16 + a;
        Yb[((size_t)b * SEQ + q) * D_MODEL + h * HD + d] = f2bf(O[f2][i] * rinv[i]);
      }
  }
}

extern "C" void kernel_launch(void* const* d_in, const int* in_sizes, int n_in,
                              void* d_out, int out_size, void* d_ws, size_t ws_size,
                              hipStream_t stream) {
  const float* x     = (const float*)d_in[0];
  const float* wqkv  = (const float*)d_in[1];
  const float* bqkv  = (const float*)d_in[2];
  const float* wproj = (const float*)d_in[3];
  const float* bproj = (const float*)d_in[4];
  float* out = (float*)d_out;
  char* ws = (char*)d_ws;
  uint16_t* xb     = (uint16_t*)(ws);                          // 16 MiB
  uint16_t* wqkvT  = (uint16_t*)(ws + 16777216);               // 6 MiB
  uint16_t* wprojT = (uint16_t*)(ws + 16777216 + 6291456);     // 2 MiB
  uint16_t* Qb     = (uint16_t*)(ws + 25165824);               // 16 MiB [B,H,S,64]
  uint16_t* Kb     = (uint16_t*)(ws + 25165824 + 16777216);    // 16 MiB [B,H,S,64]
  uint16_t* VTb    = (uint16_t*)(ws + 25165824 + 2 * 16777216);// 16 MiB [B,H,64,S] (s-permuted)
  uint16_t* Yb     = (uint16_t*)(ws + 25165824 + 3 * 16777216);// 16 MiB [B,S,H*64]

  k_cvt<<<dim3(MROWS * D_MODEL / 4 / 256), dim3(256), 0, stream>>>(x, xb, MROWS * D_MODEL / 4);
  k_tcvt<<<dim3(3 * D_MODEL / 32, D_MODEL / 32), dim3(256), 0, stream>>>(wqkv, wqkvT, D_MODEL, 3 * D_MODEL);
  k_tcvt<<<dim3(D_MODEL / 32, D_MODEL / 32), dim3(256), 0, stream>>>(wproj, wprojT, D_MODEL, D_MODEL);
  k_gemm_qkv<<<dim3(384), dim3(512), 0, stream>>>(xb, wqkvT, bqkv, Qb, Kb, VTb);
  k_attn<<<dim3(NB * NH, 8), dim3(512), 0, stream>>>(Qb, Kb, VTb, Yb);
  k_gemm_proj<<<dim3(256), dim3(512), 0, stream>>>(Yb, wprojT, bproj, out);
}